// Round 1
// baseline (683.673 us; speedup 1.0000x reference)
//
#include <hip/hip_runtime.h>
#include <hip/hip_bf16.h>

typedef __hip_bfloat16 bf16;
typedef __bf16 bf16x8 __attribute__((ext_vector_type(8)));
typedef float f32x4 __attribute__((ext_vector_type(4)));

typedef const __attribute__((address_space(1))) void GV;
typedef __attribute__((address_space(3))) void LV;

#define TM 128
#define TN 128
#define TK 64

// ---------------- cast fp32 -> bf16 (4 elems/thread) ----------------
__global__ void cast_k(const float* __restrict__ src, bf16* __restrict__ dst, int n4) {
    int i = blockIdx.x * 256 + threadIdx.x;
    if (i >= n4) return;
    float4 a = reinterpret_cast<const float4*>(src)[i];
    bf16* d = dst + (size_t)i * 4;
    d[0] = __float2bfloat16(a.x);
    d[1] = __float2bfloat16(a.y);
    d[2] = __float2bfloat16(a.z);
    d[3] = __float2bfloat16(a.w);
}

// ---------------- repack sr_w [co][ci][kh][kw] -> [co][p*512+ci] bf16 ----------------
__global__ void repack_srw_k(const float* __restrict__ srw, bf16* __restrict__ dst) {
    int idx = blockIdx.x * 256 + threadIdx.x;   // 512*2048 = 1<<20
    int co = idx >> 11;
    int t  = idx & 2047;
    int p  = t >> 9;        // kh*2+kw
    int ci = t & 511;
    dst[idx] = __float2bfloat16(srw[(size_t)co * 2048 + ci * 4 + p]);
}

// ---------------- generic bf16 GEMM, m97 structure ----------------
// KIND 0: q    = x@q_w.T + q_b, *0.125, out bf16 [b][h][n][d]
// KIND 1: xsr  = gather(x)@srw2.T + sr_b, out fp32 [8192][512]
// KIND 2: kv   = xsrln@kv_w.T + kv_b, K bf16 [b][h][m][d], V^T bf16 [b][h][d][m]
// KIND 3: out  = ao@proj_w.T + proj_b, fp32 -> d_out
template<int KIND>
__launch_bounds__(256)
__global__ void gemm_k(const bf16* __restrict__ A, const bf16* __restrict__ Bw,
                       const float* __restrict__ bias,
                       bf16* __restrict__ outB, bf16* __restrict__ outB2,
                       float* __restrict__ outF,
                       int M, int N, int K) {
    __shared__ __align__(16) bf16 ldsA[TM * TK];
    __shared__ __align__(16) bf16 ldsB[TN * TK];
    const int tid = threadIdx.x;
    const int lane = tid & 63;
    const int wave = tid >> 6;
    const int ntn = N / TN;
    const int row0 = (blockIdx.x / ntn) * TM;
    const int col0 = (blockIdx.x % ntn) * TN;
    const int wm = wave >> 1, wn = wave & 1;

    f32x4 acc[4][4];
#pragma unroll
    for (int i = 0; i < 4; ++i)
#pragma unroll
        for (int j = 0; j < 4; ++j) acc[i][j] = f32x4{0.f, 0.f, 0.f, 0.f};

    for (int k0 = 0; k0 < K; k0 += TK) {
        // stage A tile (128 x 64)
#pragma unroll
        for (int t = 0; t < 4; ++t) {
            int idx = t * 256 + tid;
            int r = idx >> 3;
            int c = (idx & 7) * 8;
            const bf16* src;
            if (KIND == 1) {
                int rr = row0 + r;
                int k = k0 + c;
                int p = k >> 9, ci = k & 511;
                int b = rr >> 10, ii = (rr >> 5) & 31, jj = rr & 31;
                int n_in = (2 * ii + (p >> 1)) * 64 + 2 * jj + (p & 1);
                src = A + ((size_t)(b * 4096 + n_in)) * 512 + ci;
            } else {
                src = A + (size_t)(row0 + r) * K + k0 + c;
            }
            __builtin_amdgcn_global_load_lds((GV*)src, (LV*)&ldsA[idx * 8], 16, 0, 0);
        }
        // stage B tile (128 x 64), Bw is [N][K] row-major
#pragma unroll
        for (int t = 0; t < 4; ++t) {
            int idx = t * 256 + tid;
            int r = idx >> 3;
            int c = (idx & 7) * 8;
            const bf16* src = Bw + (size_t)(col0 + r) * K + k0 + c;
            __builtin_amdgcn_global_load_lds((GV*)src, (LV*)&ldsB[idx * 8], 16, 0, 0);
        }
        __syncthreads();
#pragma unroll
        for (int kk = 0; kk < 2; ++kk) {
            const int kb = kk * 32 + (lane >> 4) * 8;
            bf16x8 af[4], bfr[4];
#pragma unroll
            for (int m = 0; m < 4; ++m)
                af[m] = *reinterpret_cast<const bf16x8*>(&ldsA[(wm * 64 + m * 16 + (lane & 15)) * TK + kb]);
#pragma unroll
            for (int n = 0; n < 4; ++n)
                bfr[n] = *reinterpret_cast<const bf16x8*>(&ldsB[(wn * 64 + n * 16 + (lane & 15)) * TK + kb]);
#pragma unroll
            for (int m = 0; m < 4; ++m)
#pragma unroll
                for (int n = 0; n < 4; ++n)
                    acc[m][n] = __builtin_amdgcn_mfma_f32_16x16x32_bf16(af[m], bfr[n], acc[m][n], 0, 0, 0);
        }
        __syncthreads();
    }

    // epilogue: C/D layout col = lane&15, row = (lane>>4)*4 + r
#pragma unroll
    for (int m = 0; m < 4; ++m) {
#pragma unroll
        for (int n = 0; n < 4; ++n) {
#pragma unroll
            for (int r = 0; r < 4; ++r) {
                int grow = row0 + wm * 64 + m * 16 + (lane >> 4) * 4 + r;
                int gcol = col0 + wn * 64 + n * 16 + (lane & 15);
                float v = acc[m][n][r] + bias[gcol];
                if (KIND == 0) {
                    int b = grow >> 12, nn = grow & 4095;
                    int h = gcol >> 6, dd = gcol & 63;
                    outB[(((size_t)(b * 8 + h)) * 4096 + nn) * 64 + dd] = __float2bfloat16(v * 0.125f);
                } else if (KIND == 1) {
                    outF[(size_t)grow * 512 + gcol] = v;
                } else if (KIND == 2) {
                    int b = grow >> 10, mm = grow & 1023;
                    if (gcol < 512) {
                        int h = gcol >> 6, dd = gcol & 63;
                        outB[(((size_t)(b * 8 + h)) * 1024 + mm) * 64 + dd] = __float2bfloat16(v);
                    } else {
                        int c2 = gcol - 512;
                        int h = c2 >> 6, dd = c2 & 63;
                        outB2[(((size_t)(b * 8 + h)) * 64 + dd) * 1024 + mm] = __float2bfloat16(v);
                    }
                } else {
                    outF[(size_t)grow * 512 + gcol] = v;
                }
            }
        }
    }
}

// ---------------- layernorm (fp32 in -> bf16 out), one block per row ----------------
__global__ void ln_k(const float* __restrict__ xsr, const float* __restrict__ g,
                     const float* __restrict__ bta, bf16* __restrict__ out) {
    const int row = blockIdx.x;
    const int tid = threadIdx.x;          // 256
    const float* xr = xsr + (size_t)row * 512;
    float2 v = *reinterpret_cast<const float2*>(xr + tid * 2);
    float s = v.x + v.y;
    float sq = v.x * v.x + v.y * v.y;
#pragma unroll
    for (int m = 1; m < 64; m <<= 1) {
        s += __shfl_xor(s, m, 64);
        sq += __shfl_xor(sq, m, 64);
    }
    __shared__ float rs[4], rq[4];
    int wave = tid >> 6, lane = tid & 63;
    if (lane == 0) { rs[wave] = s; rq[wave] = sq; }
    __syncthreads();
    s = rs[0] + rs[1] + rs[2] + rs[3];
    sq = rq[0] + rq[1] + rq[2] + rq[3];
    float mu = s * (1.f / 512.f);
    float var = sq * (1.f / 512.f) - mu * mu;
    float rstd = rsqrtf(var + 1e-5f);
    bf16* orow = out + (size_t)row * 512;
    orow[tid * 2]     = __float2bfloat16((v.x - mu) * rstd * g[tid * 2] + bta[tid * 2]);
    orow[tid * 2 + 1] = __float2bfloat16((v.y - mu) * rstd * g[tid * 2 + 1] + bta[tid * 2 + 1]);
}

// ---------------- flash attention: 4 waves x 16 queries, keys in tiles of 64 ----------------
__launch_bounds__(256)
__global__ void attn_k(const bf16* __restrict__ Q, const bf16* __restrict__ Kb,
                       const bf16* __restrict__ Vt, bf16* __restrict__ Out) {
    const int bid = blockIdx.x;       // B*h*64 = 4096
    const int bh = bid >> 6;
    const int qt = bid & 63;
    const int b = bh >> 3, h = bh & 7;
    const int tid = threadIdx.x, lane = tid & 63, wave = tid >> 6;
    const int q0 = qt * 64 + wave * 16;

    const bf16* Qp = Q + ((size_t)bh * 4096 + q0) * 64;
    const bf16* Kp = Kb + (size_t)bh * 1024 * 64;
    const bf16* Vp = Vt + (size_t)bh * 64 * 1024;

    __shared__ __align__(16) bf16 plds[4][16 * 64];

    const int kb0 = (lane >> 4) * 8;
    bf16x8 qf0 = *reinterpret_cast<const bf16x8*>(Qp + (lane & 15) * 64 + kb0);
    bf16x8 qf1 = *reinterpret_cast<const bf16x8*>(Qp + (lane & 15) * 64 + 32 + kb0);

    f32x4 acco[4];
#pragma unroll
    for (int i = 0; i < 4; ++i) acco[i] = f32x4{0.f, 0.f, 0.f, 0.f};
    float mrun[4], lrun[4];
#pragma unroll
    for (int r = 0; r < 4; ++r) { mrun[r] = -1e30f; lrun[r] = 0.f; }
    const f32x4 zero4 = {0.f, 0.f, 0.f, 0.f};

    for (int kt = 0; kt < 1024; kt += 64) {
        // S = Q K^T (already scaled: q was pre-scaled by 0.125)
        f32x4 s[4];
#pragma unroll
        for (int nf = 0; nf < 4; ++nf) {
            const bf16* kp = Kp + (size_t)(kt + nf * 16 + (lane & 15)) * 64 + kb0;
            bf16x8 b0 = *reinterpret_cast<const bf16x8*>(kp);
            bf16x8 b1 = *reinterpret_cast<const bf16x8*>(kp + 32);
            f32x4 t = __builtin_amdgcn_mfma_f32_16x16x32_bf16(qf0, b0, zero4, 0, 0, 0);
            s[nf] = __builtin_amdgcn_mfma_f32_16x16x32_bf16(qf1, b1, t, 0, 0, 0);
        }
        // row-max over 64 keys: in-lane over nf, then across the 16-lane group
        float mt[4];
#pragma unroll
        for (int r = 0; r < 4; ++r)
            mt[r] = fmaxf(fmaxf(s[0][r], s[1][r]), fmaxf(s[2][r], s[3][r]));
#pragma unroll
        for (int m = 1; m < 16; m <<= 1)
#pragma unroll
            for (int r = 0; r < 4; ++r) mt[r] = fmaxf(mt[r], __shfl_xor(mt[r], m, 64));

        float fac[4], sum[4];
#pragma unroll
        for (int r = 0; r < 4; ++r) {
            float mn = fmaxf(mrun[r], mt[r]);
            fac[r] = __expf(mrun[r] - mn);
            mrun[r] = mn;
            sum[r] = 0.f;
        }
        // P = exp(s - m) -> LDS (D-layout -> A-layout round trip)
#pragma unroll
        for (int nf = 0; nf < 4; ++nf)
#pragma unroll
            for (int r = 0; r < 4; ++r) {
                float p = __expf(s[nf][r] - mrun[r]);
                sum[r] += p;
                plds[wave][((lane >> 4) * 4 + r) * 64 + nf * 16 + (lane & 15)] = __float2bfloat16(p);
            }
#pragma unroll
        for (int m = 1; m < 16; m <<= 1)
#pragma unroll
            for (int r = 0; r < 4; ++r) sum[r] += __shfl_xor(sum[r], m, 64);
#pragma unroll
        for (int r = 0; r < 4; ++r) lrun[r] = lrun[r] * fac[r] + sum[r];
#pragma unroll
        for (int df = 0; df < 4; ++df)
#pragma unroll
            for (int r = 0; r < 4; ++r) acco[df][r] *= fac[r];
        __syncthreads();
        bf16x8 pa0 = *reinterpret_cast<const bf16x8*>(&plds[wave][(lane & 15) * 64 + kb0]);
        bf16x8 pa1 = *reinterpret_cast<const bf16x8*>(&plds[wave][(lane & 15) * 64 + 32 + kb0]);
#pragma unroll
        for (int df = 0; df < 4; ++df) {
            const bf16* vp = Vp + (size_t)(df * 16 + (lane & 15)) * 1024 + kt + kb0;
            bf16x8 v0 = *reinterpret_cast<const bf16x8*>(vp);
            bf16x8 v1 = *reinterpret_cast<const bf16x8*>(vp + 32);
            acco[df] = __builtin_amdgcn_mfma_f32_16x16x32_bf16(pa0, v0, acco[df], 0, 0, 0);
            acco[df] = __builtin_amdgcn_mfma_f32_16x16x32_bf16(pa1, v1, acco[df], 0, 0, 0);
        }
        __syncthreads();
    }

    float inv[4];
#pragma unroll
    for (int r = 0; r < 4; ++r) inv[r] = 1.f / lrun[r];
    bf16* outp = Out + ((size_t)b * 4096 + q0) * 512 + h * 64;
#pragma unroll
    for (int df = 0; df < 4; ++df)
#pragma unroll
        for (int r = 0; r < 4; ++r) {
            int rowq = (lane >> 4) * 4 + r;
            outp[(size_t)rowq * 512 + df * 16 + (lane & 15)] = __float2bfloat16(acco[df][r] * inv[r]);
        }
}

extern "C" void kernel_launch(void* const* d_in, const int* in_sizes, int n_in,
                              void* d_out, int out_size, void* d_ws, size_t ws_size,
                              hipStream_t stream) {
    const float* x      = (const float*)d_in[0];
    const float* q_w    = (const float*)d_in[1];
    const float* q_b    = (const float*)d_in[2];
    const float* kv_w   = (const float*)d_in[3];
    const float* kv_b   = (const float*)d_in[4];
    const float* sr_w   = (const float*)d_in[5];
    const float* sr_b   = (const float*)d_in[6];
    const float* ln_g   = (const float*)d_in[7];
    const float* ln_b   = (const float*)d_in[8];
    const float* proj_w = (const float*)d_in[9];
    const float* proj_b = (const float*)d_in[10];

    // workspace carve (bytes)
    char* w = (char*)d_ws;
    bf16* x_bf   = (bf16*)w; w += (size_t)8 * 4096 * 512 * 2;   // 33.5 MB
    bf16* q_bf   = (bf16*)w; w += (size_t)8 * 4096 * 512 * 2;   // 33.5 MB [b][h][n][d]
    bf16* qw_bf  = (bf16*)w; w += (size_t)512 * 512 * 2;
    bf16* kvw_bf = (bf16*)w; w += (size_t)1024 * 512 * 2;
    bf16* srw_bf = (bf16*)w; w += (size_t)512 * 2048 * 2;
    bf16* pjw_bf = (bf16*)w; w += (size_t)512 * 512 * 2;
    float* xsr_f = (float*)w; w += (size_t)8 * 1024 * 512 * 4;  // 16.8 MB
    bf16* xsrb   = (bf16*)w; w += (size_t)8 * 1024 * 512 * 2;   // 8.4 MB
    bf16* k_bf   = (bf16*)w; w += (size_t)8 * 8 * 1024 * 64 * 2; // [b][h][m][d]
    bf16* vt_bf  = (bf16*)w; w += (size_t)8 * 8 * 1024 * 64 * 2; // [b][h][d][m]
    bf16* ao_bf  = (bf16*)w; w += (size_t)8 * 4096 * 512 * 2;   // 33.5 MB

    // 1. casts
    cast_k<<<dim3(16384), dim3(256), 0, stream>>>(x, x_bf, 4194304);
    cast_k<<<dim3(256),  dim3(256), 0, stream>>>(q_w, qw_bf, 65536);
    cast_k<<<dim3(512),  dim3(256), 0, stream>>>(kv_w, kvw_bf, 131072);
    cast_k<<<dim3(256),  dim3(256), 0, stream>>>(proj_w, pjw_bf, 65536);
    repack_srw_k<<<dim3(4096), dim3(256), 0, stream>>>(sr_w, srw_bf);

    // 2. q = x @ q_w.T + q_b (scaled)
    gemm_k<0><<<dim3(1024), dim3(256), 0, stream>>>(x_bf, qw_bf, q_b, q_bf, nullptr, nullptr, 32768, 512, 512);
    // 3. spatial reduction conv as gathered GEMM -> fp32
    gemm_k<1><<<dim3(256), dim3(256), 0, stream>>>(x_bf, srw_bf, sr_b, nullptr, nullptr, xsr_f, 8192, 512, 2048);
    // 4. layernorm -> bf16
    ln_k<<<dim3(8192), dim3(256), 0, stream>>>(xsr_f, ln_g, ln_b, xsrb);
    // 5. kv = xsrln @ kv_w.T + kv_b -> K, V^T
    gemm_k<2><<<dim3(512), dim3(256), 0, stream>>>(xsrb, kvw_bf, kv_b, k_bf, vt_bf, nullptr, 8192, 1024, 512);
    // 6. flash attention
    attn_k<<<dim3(4096), dim3(256), 0, stream>>>(q_bf, k_bf, vt_bf, ao_bf);
    // 7. proj -> d_out (fp32)
    gemm_k<3><<<dim3(1024), dim3(256), 0, stream>>>(ao_bf, pjw_bf, proj_b, nullptr, nullptr, (float*)d_out, 32768, 512, 512);
}

// Round 2
// 432.567 us; speedup vs baseline: 1.5805x; 1.5805x over previous
//
#include <hip/hip_runtime.h>
#include <hip/hip_bf16.h>

typedef __hip_bfloat16 bf16;
typedef __bf16 bf16x8 __attribute__((ext_vector_type(8)));
typedef float f32x4 __attribute__((ext_vector_type(4)));
typedef float f32x16 __attribute__((ext_vector_type(16)));
typedef unsigned int u32;

typedef const __attribute__((address_space(1))) void GV;
typedef __attribute__((address_space(3))) void LV;

#define TM 128
#define TN 128
#define TK 64

// ---------------- cast fp32 -> bf16 (4 elems/thread) ----------------
__global__ void cast_k(const float* __restrict__ src, bf16* __restrict__ dst, int n4) {
    int i = blockIdx.x * 256 + threadIdx.x;
    if (i >= n4) return;
    float4 a = reinterpret_cast<const float4*>(src)[i];
    bf16* d = dst + (size_t)i * 4;
    d[0] = __float2bfloat16(a.x);
    d[1] = __float2bfloat16(a.y);
    d[2] = __float2bfloat16(a.z);
    d[3] = __float2bfloat16(a.w);
}

// ---------------- repack sr_w [co][ci][kh][kw] -> [co][p*512+ci] bf16 ----------------
__global__ void repack_srw_k(const float* __restrict__ srw, bf16* __restrict__ dst) {
    int idx = blockIdx.x * 256 + threadIdx.x;   // 512*2048 = 1<<20
    int co = idx >> 11;
    int t  = idx & 2047;
    int p  = t >> 9;        // kh*2+kw
    int ci = t & 511;
    dst[idx] = __float2bfloat16(srw[(size_t)co * 2048 + ci * 4 + p]);
}

// ---------------- generic bf16 GEMM, m97 structure ----------------
template<int KIND>
__launch_bounds__(256)
__global__ void gemm_k(const bf16* __restrict__ A, const bf16* __restrict__ Bw,
                       const float* __restrict__ bias,
                       bf16* __restrict__ outB, bf16* __restrict__ outB2,
                       float* __restrict__ outF,
                       int M, int N, int K) {
    __shared__ __align__(16) bf16 ldsA[TM * TK];
    __shared__ __align__(16) bf16 ldsB[TN * TK];
    const int tid = threadIdx.x;
    const int lane = tid & 63;
    const int wave = tid >> 6;
    const int ntn = N / TN;
    const int row0 = (blockIdx.x / ntn) * TM;
    const int col0 = (blockIdx.x % ntn) * TN;
    const int wm = wave >> 1, wn = wave & 1;

    f32x4 acc[4][4];
#pragma unroll
    for (int i = 0; i < 4; ++i)
#pragma unroll
        for (int j = 0; j < 4; ++j) acc[i][j] = f32x4{0.f, 0.f, 0.f, 0.f};

    for (int k0 = 0; k0 < K; k0 += TK) {
#pragma unroll
        for (int t = 0; t < 4; ++t) {
            int idx = t * 256 + tid;
            int r = idx >> 3;
            int c = (idx & 7) * 8;
            const bf16* src;
            if (KIND == 1) {
                int rr = row0 + r;
                int k = k0 + c;
                int p = k >> 9, ci = k & 511;
                int b = rr >> 10, ii = (rr >> 5) & 31, jj = rr & 31;
                int n_in = (2 * ii + (p >> 1)) * 64 + 2 * jj + (p & 1);
                src = A + ((size_t)(b * 4096 + n_in)) * 512 + ci;
            } else {
                src = A + (size_t)(row0 + r) * K + k0 + c;
            }
            __builtin_amdgcn_global_load_lds((GV*)src, (LV*)&ldsA[idx * 8], 16, 0, 0);
        }
#pragma unroll
        for (int t = 0; t < 4; ++t) {
            int idx = t * 256 + tid;
            int r = idx >> 3;
            int c = (idx & 7) * 8;
            const bf16* src = Bw + (size_t)(col0 + r) * K + k0 + c;
            __builtin_amdgcn_global_load_lds((GV*)src, (LV*)&ldsB[idx * 8], 16, 0, 0);
        }
        __syncthreads();
#pragma unroll
        for (int kk = 0; kk < 2; ++kk) {
            const int kb = kk * 32 + (lane >> 4) * 8;
            bf16x8 af[4], bfr[4];
#pragma unroll
            for (int m = 0; m < 4; ++m)
                af[m] = *reinterpret_cast<const bf16x8*>(&ldsA[(wm * 64 + m * 16 + (lane & 15)) * TK + kb]);
#pragma unroll
            for (int n = 0; n < 4; ++n)
                bfr[n] = *reinterpret_cast<const bf16x8*>(&ldsB[(wn * 64 + n * 16 + (lane & 15)) * TK + kb]);
#pragma unroll
            for (int m = 0; m < 4; ++m)
#pragma unroll
                for (int n = 0; n < 4; ++n)
                    acc[m][n] = __builtin_amdgcn_mfma_f32_16x16x32_bf16(af[m], bfr[n], acc[m][n], 0, 0, 0);
        }
        __syncthreads();
    }

#pragma unroll
    for (int m = 0; m < 4; ++m) {
#pragma unroll
        for (int n = 0; n < 4; ++n) {
#pragma unroll
            for (int r = 0; r < 4; ++r) {
                int grow = row0 + wm * 64 + m * 16 + (lane >> 4) * 4 + r;
                int gcol = col0 + wn * 64 + n * 16 + (lane & 15);
                float v = acc[m][n][r] + bias[gcol];
                if (KIND == 0) {
                    int b = grow >> 12, nn = grow & 4095;
                    int h = gcol >> 6, dd = gcol & 63;
                    outB[(((size_t)(b * 8 + h)) * 4096 + nn) * 64 + dd] = __float2bfloat16(v * 0.125f);
                } else if (KIND == 1) {
                    outF[(size_t)grow * 512 + gcol] = v;
                } else if (KIND == 2) {
                    int b = grow >> 10, mm = grow & 1023;
                    if (gcol < 512) {
                        int h = gcol >> 6, dd = gcol & 63;
                        outB[(((size_t)(b * 8 + h)) * 1024 + mm) * 64 + dd] = __float2bfloat16(v);
                    } else {
                        int c2 = gcol - 512;
                        int h = c2 >> 6, dd = c2 & 63;
                        outB2[(((size_t)(b * 8 + h)) * 64 + dd) * 1024 + mm] = __float2bfloat16(v);
                    }
                } else {
                    outF[(size_t)grow * 512 + gcol] = v;
                }
            }
        }
    }
}

// ---------------- layernorm (fp32 in -> bf16 out), one block per row ----------------
__global__ void ln_k(const float* __restrict__ xsr, const float* __restrict__ g,
                     const float* __restrict__ bta, bf16* __restrict__ out) {
    const int row = blockIdx.x;
    const int tid = threadIdx.x;          // 256
    const float* xr = xsr + (size_t)row * 512;
    float2 v = *reinterpret_cast<const float2*>(xr + tid * 2);
    float s = v.x + v.y;
    float sq = v.x * v.x + v.y * v.y;
#pragma unroll
    for (int m = 1; m < 64; m <<= 1) {
        s += __shfl_xor(s, m, 64);
        sq += __shfl_xor(sq, m, 64);
    }
    __shared__ float rs[4], rq[4];
    int wave = tid >> 6, lane = tid & 63;
    if (lane == 0) { rs[wave] = s; rq[wave] = sq; }
    __syncthreads();
    s = rs[0] + rs[1] + rs[2] + rs[3];
    sq = rq[0] + rq[1] + rq[2] + rq[3];
    float mu = s * (1.f / 512.f);
    float var = sq * (1.f / 512.f) - mu * mu;
    float rstd = rsqrtf(var + 1e-5f);
    bf16* orow = out + (size_t)row * 512;
    orow[tid * 2]     = __float2bfloat16((v.x - mu) * rstd * g[tid * 2] + bta[tid * 2]);
    orow[tid * 2 + 1] = __float2bfloat16((v.y - mu) * rstd * g[tid * 2 + 1] + bta[tid * 2 + 1]);
}

// ---------------- flash attention, swapped-operand, 32 queries/wave ----------------
// Q: [bh][n][64] (pre-scaled), K: [bh][m][64], Vt: [bh][64][m], Out: [b][n][512]
__launch_bounds__(256)
__global__ void attn_k(const bf16* __restrict__ Q, const bf16* __restrict__ Kb,
                       const bf16* __restrict__ Vt, bf16* __restrict__ Out) {
    const int bid = blockIdx.x;       // 64 bh * 32 qb = 2048
    const int bh = bid >> 5;
    const int qb = bid & 31;
    const int b = bh >> 3, h = bh & 7;
    const int tid = threadIdx.x, lane = tid & 63, wave = tid >> 6;
    const int q0 = qb * 128 + wave * 32;
    const int l31 = lane & 31;
    const int klo8 = (lane >> 5) * 8;    // which 8-k-sub-block this half-wave owns
    const bool hi = lane >= 32;

    const bf16* Qp = Q + ((size_t)bh * 4096 + q0) * 64;
    const bf16* Kp = Kb + (size_t)bh * 1024 * 64;
    const bf16* Vp = Vt + (size_t)bh * 64 * 1024;

    // Q fragments (B-operand of swapped QK^T): col=query=l31, k=d contiguous
    bf16x8 qf[4];
#pragma unroll
    for (int c = 0; c < 4; ++c)
        qf[c] = *reinterpret_cast<const bf16x8*>(Qp + (size_t)l31 * 64 + c * 16 + klo8);

    f32x16 accO[2];
    accO[0] = f32x16{};
    accO[1] = f32x16{};
    float mrun = -1e30f, lrun = 0.f;

    for (int kt = 0; kt < 1024; kt += 32) {
        // S^T = K . Q^T  (A = K-frag: row=key, k=d)
        f32x16 s = f32x16{};
#pragma unroll
        for (int c = 0; c < 4; ++c) {
            bf16x8 kf = *reinterpret_cast<const bf16x8*>(
                Kp + (size_t)(kt + l31) * 64 + c * 16 + klo8);
            s = __builtin_amdgcn_mfma_f32_32x32x16_bf16(kf, qf[c], s, 0, 0, 0);
        }
        // lane-local row-max over the 16 in-lane keys, then combine with partner half
        float mt = s[0];
#pragma unroll
        for (int r = 1; r < 16; ++r) mt = fmaxf(mt, s[r]);
        mt = fmaxf(mt, __shfl_xor(mt, 32, 64));

        // defer-max (T13): only rescale when the max actually grew
        if (!__all(mt - mrun <= 8.f)) {
            float mn = fmaxf(mrun, mt);
            float fac = __expf(mrun - mn);
            lrun *= fac;
#pragma unroll
            for (int dd = 0; dd < 2; ++dd)
#pragma unroll
                for (int r = 0; r < 16; ++r) accO[dd][r] *= fac;
            mrun = mn;
        }

        // P = exp(S - m), in-lane sum, pack to bf16 pairs
        float p[16];
        float lsum = 0.f;
#pragma unroll
        for (int r = 0; r < 16; ++r) {
            p[r] = __expf(s[r] - mrun);
            lsum = lsum + p[r];
        }
        lsum += __shfl_xor(lsum, 32, 64);
        lrun += lsum;

        u32 w[8], rr[8];
#pragma unroll
        for (int k = 0; k < 8; ++k) {
            union { struct { unsigned short lo, hi16; } ss; u32 u; } cv;
            cv.ss.lo   = __builtin_bit_cast(unsigned short, __float2bfloat16(p[2 * k]));
            cv.ss.hi16 = __builtin_bit_cast(unsigned short, __float2bfloat16(p[2 * k + 1]));
            w[k] = cv.u;
        }
#pragma unroll
        for (int k = 0; k < 8; ++k) rr[k] = __shfl_xor(w[k], 32, 64);

        // assemble P^T B-fragments (key chunk 0: keys 0-15, chunk 1: keys 16-31)
        union { u32 u[4]; bf16x8 v; } f0, f1;
        f0.u[0] = hi ? rr[2] : w[0];
        f0.u[1] = hi ? rr[3] : w[1];
        f0.u[2] = hi ? w[2]  : rr[0];
        f0.u[3] = hi ? w[3]  : rr[1];
        f1.u[0] = hi ? rr[6] : w[4];
        f1.u[1] = hi ? rr[7] : w[5];
        f1.u[2] = hi ? w[6]  : rr[4];
        f1.u[3] = hi ? w[7]  : rr[5];

        // O^T += V^T . P^T   (A = V^T-frag: row=d, k=key contiguous in m)
#pragma unroll
        for (int dd = 0; dd < 2; ++dd) {
            const bf16* vp = Vp + (size_t)(dd * 32 + l31) * 1024 + kt;
            bf16x8 v0 = *reinterpret_cast<const bf16x8*>(vp + klo8);
            bf16x8 v1 = *reinterpret_cast<const bf16x8*>(vp + 16 + klo8);
            accO[dd] = __builtin_amdgcn_mfma_f32_32x32x16_bf16(v0, f0.v, accO[dd], 0, 0, 0);
            accO[dd] = __builtin_amdgcn_mfma_f32_32x32x16_bf16(v1, f1.v, accO[dd], 0, 0, 0);
        }
    }

    // epilogue: O^T (d-major in regs) -> LDS [q][d] -> coalesced global store
    __shared__ __align__(16) bf16 obuf[4][32][72];
    float inv = 1.f / lrun;
#pragma unroll
    for (int dd = 0; dd < 2; ++dd)
#pragma unroll
        for (int r = 0; r < 16; r += 2) {
            int d = dd * 32 + (r & 3) + 8 * (r >> 2) + 4 * (lane >> 5);
            union { struct { unsigned short lo, hi16; } ss; u32 u; } cv;
            cv.ss.lo   = __builtin_bit_cast(unsigned short, __float2bfloat16(accO[dd][r] * inv));
            cv.ss.hi16 = __builtin_bit_cast(unsigned short, __float2bfloat16(accO[dd][r + 1] * inv));
            *reinterpret_cast<u32*>(&obuf[wave][l31][d]) = cv.u;
        }
    __syncthreads();
    {
        int qr = lane >> 1, hf = lane & 1;
        const bf16* orow = &obuf[wave][qr][hf * 32];
        bf16* gout = Out + ((size_t)b * 4096 + q0 + qr) * 512 + h * 64 + hf * 32;
#pragma unroll
        for (int j = 0; j < 4; ++j) {
            bf16x8 t = *reinterpret_cast<const bf16x8*>(orow + j * 8);
            *reinterpret_cast<bf16x8*>(gout + j * 8) = t;
        }
    }
}

extern "C" void kernel_launch(void* const* d_in, const int* in_sizes, int n_in,
                              void* d_out, int out_size, void* d_ws, size_t ws_size,
                              hipStream_t stream) {
    const float* x      = (const float*)d_in[0];
    const float* q_w    = (const float*)d_in[1];
    const float* q_b    = (const float*)d_in[2];
    const float* kv_w   = (const float*)d_in[3];
    const float* kv_b   = (const float*)d_in[4];
    const float* sr_w   = (const float*)d_in[5];
    const float* sr_b   = (const float*)d_in[6];
    const float* ln_g   = (const float*)d_in[7];
    const float* ln_b   = (const float*)d_in[8];
    const float* proj_w = (const float*)d_in[9];
    const float* proj_b = (const float*)d_in[10];

    char* w = (char*)d_ws;
    bf16* x_bf   = (bf16*)w; w += (size_t)8 * 4096 * 512 * 2;
    bf16* q_bf   = (bf16*)w; w += (size_t)8 * 4096 * 512 * 2;
    bf16* qw_bf  = (bf16*)w; w += (size_t)512 * 512 * 2;
    bf16* kvw_bf = (bf16*)w; w += (size_t)1024 * 512 * 2;
    bf16* srw_bf = (bf16*)w; w += (size_t)512 * 2048 * 2;
    bf16* pjw_bf = (bf16*)w; w += (size_t)512 * 512 * 2;
    float* xsr_f = (float*)w; w += (size_t)8 * 1024 * 512 * 4;
    bf16* xsrb   = (bf16*)w; w += (size_t)8 * 1024 * 512 * 2;
    bf16* k_bf   = (bf16*)w; w += (size_t)8 * 8 * 1024 * 64 * 2;
    bf16* vt_bf  = (bf16*)w; w += (size_t)8 * 8 * 1024 * 64 * 2;
    bf16* ao_bf  = (bf16*)w; w += (size_t)8 * 4096 * 512 * 2;

    cast_k<<<dim3(16384), dim3(256), 0, stream>>>(x, x_bf, 4194304);
    cast_k<<<dim3(256),  dim3(256), 0, stream>>>(q_w, qw_bf, 65536);
    cast_k<<<dim3(512),  dim3(256), 0, stream>>>(kv_w, kvw_bf, 131072);
    cast_k<<<dim3(256),  dim3(256), 0, stream>>>(proj_w, pjw_bf, 65536);
    repack_srw_k<<<dim3(4096), dim3(256), 0, stream>>>(sr_w, srw_bf);

    gemm_k<0><<<dim3(1024), dim3(256), 0, stream>>>(x_bf, qw_bf, q_b, q_bf, nullptr, nullptr, 32768, 512, 512);
    gemm_k<1><<<dim3(256), dim3(256), 0, stream>>>(x_bf, srw_bf, sr_b, nullptr, nullptr, xsr_f, 8192, 512, 2048);
    ln_k<<<dim3(8192), dim3(256), 0, stream>>>(xsr_f, ln_g, ln_b, xsrb);
    gemm_k<2><<<dim3(512), dim3(256), 0, stream>>>(xsrb, kvw_bf, kv_b, k_bf, vt_bf, nullptr, 8192, 1024, 512);
    attn_k<<<dim3(2048), dim3(256), 0, stream>>>(q_bf, k_bf, vt_bf, ao_bf);
    gemm_k<3><<<dim3(1024), dim3(256), 0, stream>>>(ao_bf, pjw_bf, proj_b, nullptr, nullptr, (float*)d_out, 32768, 512, 512);
}